// Round 3
// baseline (130.055 us; speedup 1.0000x reference)
//
#include <hip/hip_runtime.h>

#define NB 4
#define VD 128
#define NSTEPS 226
#define LPR 16         // lanes per ray

// ---------------------------------------------------------------------------
// One kernel: each thread recomputes its batch's ray_mat/source (same f32 op
// order as the JAX reference), then marches steps phase, phase+LPR, ... with
// a precomputed exact trip count (no per-step branch -> pipelinable).
// ---------------------------------------------------------------------------
__global__ __launch_bounds__(256) void drr_proj_kernel(const float* __restrict__ vol,
                                                       const float* __restrict__ tp,
                                                       float* __restrict__ out) {
    const int gtid = blockIdx.x * blockDim.x + threadIdx.x;
    const int ray   = gtid >> 4;        // gtid / LPR
    const int phase = gtid & (LPR - 1);

    const int b = ray >> 14;            // 16384 rays per batch
    const int p = ray & 16383;
    const int h = p >> 7;               // u index
    const int w = p & 127;              // v index

    // ---- per-batch setup (identical op order to reference) ----
    const float* q = tp + b * 6;
    const float thx = q[0], thy = q[1], thz = q[2];
    const float t0 = -q[3];
    const float t1 = -q[4];
    const float t2 = (-q[5]) + 1000.0f;

    const float cxx = cosf(thx), sxx = sinf(thx);
    const float cyy = cosf(thy), syy = sinf(thy);
    const float czz = cosf(thz), szz = sinf(thz);

    // A = Rx @ Ry
    const float A00 = cyy;          const float A01 = 0.0f; const float A02 = syy;
    const float A10 = sxx*syy;      const float A11 = cxx;  const float A12 = (-sxx)*cyy;
    const float A20 = cxx*(-syy);   const float A21 = sxx;  const float A22 = cxx*cyy;

    // R = A @ Rz
    const float R00 = A00*czz + A01*szz;
    const float R01 = A00*(-szz) + A01*czz;
    const float R02 = A02;
    const float R10 = A10*czz + A11*szz;
    const float R11 = A10*(-szz) + A11*czz;
    const float R12 = A12;
    const float R20 = A20*czz + A21*szz;
    const float R21 = A20*(-szz) + A21*czz;
    const float R22 = A22;

    // Rt = R^T
    const float Rt00 = R00, Rt01 = R10, Rt02 = R20;
    const float Rt10 = R01, Rt11 = R11, Rt12 = R21;
    const float Rt20 = R02, Rt21 = R12, Rt22 = R22;

    // K_inv entries (folded at compile time, double -> float like np.linalg.inv)
    const float ki00 = (float)(1.0 / (1500.0 / 1.5));
    const float ki11 = (float)(1.0 / (1500.0 / 1.5));
    const float ki02 = (float)((0.0 - 64.0) / (1500.0 / 1.5));
    const float ki12 = (float)((0.0 - 64.0) / (1500.0 / 1.5));

    const float M00 = Rt00 * ki00;
    const float M01 = Rt01 * ki11;
    const float M02 = (Rt00 * ki02 + Rt01 * ki12) + Rt02;
    const float M10 = Rt10 * ki00;
    const float M11 = Rt11 * ki11;
    const float M12 = (Rt10 * ki02 + Rt11 * ki12) + Rt12;
    const float M20 = Rt20 * ki00;
    const float M21 = Rt21 * ki11;
    const float M22 = (Rt20 * ki02 + Rt21 * ki12) + Rt22;

    const float sx = 64.0f - ((Rt00*t0 + Rt01*t1) + Rt02*t2);
    const float sy = 64.0f - ((Rt10*t0 + Rt11*t1) + Rt12*t2);
    const float sz = 64.0f - ((Rt20*t0 + Rt21*t1) + Rt22*t2);

    // ---- per-ray setup ----
    const float u = (float)h + 0.5f;
    const float v = (float)w + 0.5f;

    float dx = (M00*u + M01*v) + M02;
    float dy = (M10*u + M11*v) + M12;
    float dz = (M20*u + M21*v) + M22;
    const float phys = sqrtf((dx*dx + dy*dy) + dz*dz);
    dx /= phys; dy /= phys; dz /= phys;

    const float sdx = (fabsf(dx) < 1e-8f) ? 1e-8f : dx;
    const float sdy = (fabsf(dy) < 1e-8f) ? 1e-8f : dy;
    const float sdz = (fabsf(dz) < 1e-8f) ? 1e-8f : dz;

    const float t0x = (0.0f - sx) / sdx, t1x = (128.0f - sx) / sdx;
    const float t0y = (0.0f - sy) / sdy, t1y = (128.0f - sy) / sdy;
    const float t0z = (0.0f - sz) / sdz, t1z = (128.0f - sz) / sdz;

    float tmin = fmaxf(fmaxf(fminf(t0x, t1x), fminf(t0y, t1y)), fminf(t0z, t1z));
    tmin = fmaxf(tmin, 0.0f);
    const float tmax = fminf(fminf(fmaxf(t0x, t1x), fmaxf(t0y, t1y)), fmaxf(t0z, t1z));

    // ---- exact trip count: #k in [0,NSTEPS) with tmin + (k+0.5) < tmax ----
    int nk = (int)ceilf(tmax - tmin - 0.5f);
    nk = max(0, min(NSTEPS, nk));
    while (nk < NSTEPS && (tmin + ((float)nk + 0.5f) < tmax)) ++nk;
    while (nk > 0 && !(tmin + ((float)(nk - 1) + 0.5f) < tmax)) --nk;

    const int myn = (nk > phase) ? ((nk - phase + LPR - 1) >> 4) : 0;

    const float* volb = vol + (size_t)b * (VD * VD * VD);

    float acc = 0.0f;
    #pragma unroll 2
    for (int i = 0; i < myn; ++i) {
        const int k = phase + (i << 4);
        const float ts = tmin + ((float)k + 0.5f);   // same arithmetic as reference

        const float px = sx + ts * dx;
        const float py = sy + ts * dy;
        const float pz = sz + ts * dz;

        const float fx = floorf(px), fy = floorf(py), fz = floorf(pz);
        const int ix = (int)fx, iy = (int)fy, iz = (int)fz;
        const float frx = px - fx, fry = py - fy, frz = pz - fz;

        const float wx1 = frx, wx0 = 1.0f - frx;
        const float wy1 = fry, wy0 = 1.0f - fry;
        const float wz1 = frz, wz0 = 1.0f - frz;

        const int ix1 = ix + 1, iy1 = iy + 1, iz1 = iz + 1;
        const bool vx0 = (ix  >= 0) && (ix  < VD);
        const bool vx1 = (ix1 >= 0) && (ix1 < VD);
        const bool vy0 = (iy  >= 0) && (iy  < VD);
        const bool vy1 = (iy1 >= 0) && (iy1 < VD);
        const bool vz0 = (iz  >= 0) && (iz  < VD);
        const bool vz1 = (iz1 >= 0) && (iz1 < VD);

        const int cx0 = min(max(ix,  0), VD - 1), cx1 = min(max(ix1, 0), VD - 1);
        const int cy0 = min(max(iy,  0), VD - 1), cy1 = min(max(iy1, 0), VD - 1);
        const int cz0 = min(max(iz,  0), VD - 1), cz1 = min(max(iz1, 0), VD - 1);

        const int bx0 = cx0 * (VD * VD), bx1 = cx1 * (VD * VD);
        const int by0 = cy0 * VD,        by1 = cy1 * VD;

        float smp = 0.0f;
        smp += ((vx0 && vy0 && vz0) ? volb[bx0 + by0 + cz0] : 0.0f) * ((wx0 * wy0) * wz0);
        smp += ((vx0 && vy0 && vz1) ? volb[bx0 + by0 + cz1] : 0.0f) * ((wx0 * wy0) * wz1);
        smp += ((vx0 && vy1 && vz0) ? volb[bx0 + by1 + cz0] : 0.0f) * ((wx0 * wy1) * wz0);
        smp += ((vx0 && vy1 && vz1) ? volb[bx0 + by1 + cz1] : 0.0f) * ((wx0 * wy1) * wz1);
        smp += ((vx1 && vy0 && vz0) ? volb[bx1 + by0 + cz0] : 0.0f) * ((wx1 * wy0) * wz0);
        smp += ((vx1 && vy0 && vz1) ? volb[bx1 + by0 + cz1] : 0.0f) * ((wx1 * wy0) * wz1);
        smp += ((vx1 && vy1 && vz0) ? volb[bx1 + by1 + cz0] : 0.0f) * ((wx1 * wy1) * wz0);
        smp += ((vx1 && vy1 && vz1) ? volb[bx1 + by1 + cz1] : 0.0f) * ((wx1 * wy1) * wz1);

        acc += smp;
    }

    // 16-lane butterfly reduce within the ray's lane group
    acc += __shfl_xor(acc, 1, 64);
    acc += __shfl_xor(acc, 2, 64);
    acc += __shfl_xor(acc, 4, 64);
    acc += __shfl_xor(acc, 8, 64);

    if (phase == 0) out[ray] = acc / 10.0f;
}

extern "C" void kernel_launch(void* const* d_in, const int* in_sizes, int n_in,
                              void* d_out, int out_size, void* d_ws, size_t ws_size,
                              hipStream_t stream) {
    const float* vol = (const float*)d_in[0];   // (4,1,128,128,128) f32
    const float* tp  = (const float*)d_in[1];   // (4,6) f32
    float* out = (float*)d_out;                 // (4,1,128,128) f32
    (void)d_ws; (void)ws_size;

    const int total_threads = NB * VD * VD * LPR;   // 1048576
    hipLaunchKernelGGL(drr_proj_kernel, dim3(total_threads / 256), dim3(256), 0, stream,
                       vol, tp, out);
}

// Round 4
// 102.900 us; speedup vs baseline: 1.2639x; 1.2639x over previous
//
#include <hip/hip_runtime.h>

#define NB 4
#define VD 128
#define NSTEPS 226
#define LPR 16         // lanes per ray

// ---------------------------------------------------------------------------
// Setup kernel: per batch, compute ray_mat = R^T @ K_inv (3x3) and source (3)
// in the same f32 operation order as the JAX reference. Written to ws.
// ---------------------------------------------------------------------------
__global__ void drr_setup_kernel(const float* __restrict__ tp, float* __restrict__ ws) {
    int b = threadIdx.x;
    if (b >= NB) return;
    const float* q = tp + b * 6;
    float thx = q[0], thy = q[1], thz = q[2];
    float t0 = -q[3];
    float t1 = -q[4];
    float t2 = (-q[5]) + 1000.0f;

    float cxx = cosf(thx), sxx = sinf(thx);
    float cyy = cosf(thy), syy = sinf(thy);
    float czz = cosf(thz), szz = sinf(thz);

    // A = Rx @ Ry
    float A00 = cyy;          float A01 = 0.0f; float A02 = syy;
    float A10 = sxx*syy;      float A11 = cxx;  float A12 = (-sxx)*cyy;
    float A20 = cxx*(-syy);   float A21 = sxx;  float A22 = cxx*cyy;

    // R = A @ Rz
    float R00 = A00*czz + A01*szz;
    float R01 = A00*(-szz) + A01*czz;
    float R02 = A02;
    float R10 = A10*czz + A11*szz;
    float R11 = A10*(-szz) + A11*czz;
    float R12 = A12;
    float R20 = A20*czz + A21*szz;
    float R21 = A20*(-szz) + A21*czz;
    float R22 = A22;

    // Rt = R^T
    float Rt00 = R00, Rt01 = R10, Rt02 = R20;
    float Rt10 = R01, Rt11 = R11, Rt12 = R21;
    float Rt20 = R02, Rt21 = R12, Rt22 = R22;

    const float ki00 = (float)(1.0 / (1500.0 / 1.5));
    const float ki11 = (float)(1.0 / (1500.0 / 1.5));
    const float ki02 = (float)((0.0 - 64.0) / (1500.0 / 1.5));
    const float ki12 = (float)((0.0 - 64.0) / (1500.0 / 1.5));

    float M00 = Rt00 * ki00;
    float M01 = Rt01 * ki11;
    float M02 = (Rt00 * ki02 + Rt01 * ki12) + Rt02;
    float M10 = Rt10 * ki00;
    float M11 = Rt11 * ki11;
    float M12 = (Rt10 * ki02 + Rt11 * ki12) + Rt12;
    float M20 = Rt20 * ki00;
    float M21 = Rt21 * ki11;
    float M22 = (Rt20 * ki02 + Rt21 * ki12) + Rt22;

    float s0 = 64.0f - ((Rt00*t0 + Rt01*t1) + Rt02*t2);
    float s1 = 64.0f - ((Rt10*t0 + Rt11*t1) + Rt12*t2);
    float s2 = 64.0f - ((Rt20*t0 + Rt21*t1) + Rt22*t2);

    float* o = ws + b * 16;
    o[0] = M00; o[1] = M01; o[2] = M02;
    o[3] = M10; o[4] = M11; o[5] = M12;
    o[6] = M20; o[7] = M21; o[8] = M22;
    o[9] = s0;  o[10] = s1; o[11] = s2;
}

// ---------------------------------------------------------------------------
// Main kernel: LPR lanes per ray, lane j marches steps j, j+LPR, ...
// March is split into [0,ka) checked / [ka,kb) interior-fast / [kb,nk) checked.
// ---------------------------------------------------------------------------
__global__ __launch_bounds__(256) void drr_proj_kernel(const float* __restrict__ vol,
                                                       const float* __restrict__ ws,
                                                       float* __restrict__ out) {
    const int gtid = blockIdx.x * blockDim.x + threadIdx.x;
    const int ray   = gtid >> 4;        // gtid / LPR
    const int phase = gtid & (LPR - 1);

    const int b = ray >> 14;            // 16384 rays per batch
    const int p = ray & 16383;
    const int h = p >> 7;               // u index
    const int w = p & 127;              // v index

    const float* wb = ws + b * 16;
    const float M00 = wb[0], M01 = wb[1], M02 = wb[2];
    const float M10 = wb[3], M11 = wb[4], M12 = wb[5];
    const float M20 = wb[6], M21 = wb[7], M22 = wb[8];
    const float sx = wb[9], sy = wb[10], sz = wb[11];

    const float u = (float)h + 0.5f;
    const float v = (float)w + 0.5f;

    float dx = (M00*u + M01*v) + M02;
    float dy = (M10*u + M11*v) + M12;
    float dz = (M20*u + M21*v) + M22;
    const float phys = sqrtf((dx*dx + dy*dy) + dz*dz);
    dx /= phys; dy /= phys; dz /= phys;

    const float sdx = (fabsf(dx) < 1e-8f) ? 1e-8f : dx;
    const float sdy = (fabsf(dy) < 1e-8f) ? 1e-8f : dy;
    const float sdz = (fabsf(dz) < 1e-8f) ? 1e-8f : dz;

    const float t0x = (0.0f - sx) / sdx, t1x = (128.0f - sx) / sdx;
    const float t0y = (0.0f - sy) / sdy, t1y = (128.0f - sy) / sdy;
    const float t0z = (0.0f - sz) / sdz, t1z = (128.0f - sz) / sdz;

    float tmin = fmaxf(fmaxf(fminf(t0x, t1x), fminf(t0y, t1y)), fminf(t0z, t1z));
    tmin = fmaxf(tmin, 0.0f);
    const float tmax = fminf(fminf(fmaxf(t0x, t1x), fmaxf(t0y, t1y)), fmaxf(t0z, t1z));

    // ---- exact trip count: #k in [0,NSTEPS) with tmin + (k+0.5) < tmax ----
    int nk = (int)ceilf(tmax - tmin - 0.5f);
    nk = max(0, min(NSTEPS, nk));
    while (nk < NSTEPS && (tmin + ((float)nk + 0.5f) < tmax)) ++nk;
    while (nk > 0 && !(tmin + ((float)(nk - 1) + 0.5f) < tmax)) --nk;

    // ---- conservative interior step range [ka, kb): guarantees all 8 corners
    // in-bounds (px in [0,127) etc.) with >=0.4 voxel margin. Fast path below
    // is bit-exact with the checked path for such samples.
    {
        // t at px = 0.5 and 126.5 via exact linear interp of slab t's
        const float rx = t1x - t0x, ry = t1y - t0y, rz = t1z - t0z;
        const float ax0 = t0x + 0.00390625f * rx, ax1 = t0x + 0.98828125f * rx;
        const float ay0 = t0y + 0.00390625f * ry, ay1 = t0y + 0.98828125f * ry;
        const float az0 = t0z + 0.00390625f * rz, az1 = t0z + 0.98828125f * rz;
        const float enx = fminf(ax0, ax1), exx = fmaxf(ax0, ax1);
        const float eny = fminf(ay0, ay1), exy = fmaxf(ay0, ay1);
        const float enz = fminf(az0, az1), exz = fmaxf(az0, az1);
        const float tin  = fmaxf(fmaxf(enx, eny), enz);
        const float tout = fminf(fminf(exx, exy), exz);
        int ka = (int)ceilf(tin - tmin - 0.5f) + 1;    // +1 step safety
        int kb = (int)floorf(tout - tmin - 0.5f) - 1;  // kb inclusive-1 → make exclusive below
        ka = max(0, min(nk, ka));
        kb = max(ka, min(nk, kb));                     // [ka, kb) exclusive
        // stash in registers for loop-bound computation
        // per-lane iteration bounds: i covers k = phase + 16*i
        const int myn = (nk > phase) ? ((nk - phase + LPR - 1) >> 4) : 0;
        int iA = (ka > phase) ? ((ka - phase + LPR - 1) >> 4) : 0;  iA = min(iA, myn);
        int iB = (kb > phase) ? ((kb - phase + LPR - 1) >> 4) : 0;  iB = min(max(iB, iA), myn);

        const float* volb = vol + (size_t)b * (VD * VD * VD);
        float acc = 0.0f;

        // checked body (valid for any k)
        auto slow_step = [&](int k) {
            const float ts = tmin + ((float)k + 0.5f);
            const float px = sx + ts * dx;
            const float py = sy + ts * dy;
            const float pz = sz + ts * dz;
            const float fx = floorf(px), fy = floorf(py), fz = floorf(pz);
            const int ix = (int)fx, iy = (int)fy, iz = (int)fz;
            const float frx = px - fx, fry = py - fy, frz = pz - fz;
            const float wx1 = frx, wx0 = 1.0f - frx;
            const float wy1 = fry, wy0 = 1.0f - fry;
            const float wz1 = frz, wz0 = 1.0f - frz;
            const int ix1 = ix + 1, iy1 = iy + 1, iz1 = iz + 1;
            const bool vx0 = (ix  >= 0) && (ix  < VD);
            const bool vx1 = (ix1 >= 0) && (ix1 < VD);
            const bool vy0 = (iy  >= 0) && (iy  < VD);
            const bool vy1 = (iy1 >= 0) && (iy1 < VD);
            const bool vz0 = (iz  >= 0) && (iz  < VD);
            const bool vz1 = (iz1 >= 0) && (iz1 < VD);
            const int cx0 = min(max(ix,  0), VD - 1), cx1 = min(max(ix1, 0), VD - 1);
            const int cy0 = min(max(iy,  0), VD - 1), cy1 = min(max(iy1, 0), VD - 1);
            const int cz0 = min(max(iz,  0), VD - 1), cz1 = min(max(iz1, 0), VD - 1);
            const int bx0 = cx0 * (VD * VD), bx1 = cx1 * (VD * VD);
            const int by0 = cy0 * VD,        by1 = cy1 * VD;
            float smp = 0.0f;
            smp += ((vx0 && vy0 && vz0) ? volb[bx0 + by0 + cz0] : 0.0f) * ((wx0 * wy0) * wz0);
            smp += ((vx0 && vy0 && vz1) ? volb[bx0 + by0 + cz1] : 0.0f) * ((wx0 * wy0) * wz1);
            smp += ((vx0 && vy1 && vz0) ? volb[bx0 + by1 + cz0] : 0.0f) * ((wx0 * wy1) * wz0);
            smp += ((vx0 && vy1 && vz1) ? volb[bx0 + by1 + cz1] : 0.0f) * ((wx0 * wy1) * wz1);
            smp += ((vx1 && vy0 && vz0) ? volb[bx1 + by0 + cz0] : 0.0f) * ((wx1 * wy0) * wz0);
            smp += ((vx1 && vy0 && vz1) ? volb[bx1 + by0 + cz1] : 0.0f) * ((wx1 * wy0) * wz1);
            smp += ((vx1 && vy1 && vz0) ? volb[bx1 + by1 + cz0] : 0.0f) * ((wx1 * wy1) * wz0);
            smp += ((vx1 && vy1 && vz1) ? volb[bx1 + by1 + cz1] : 0.0f) * ((wx1 * wy1) * wz1);
            acc += smp;
        };

        #pragma unroll 1
        for (int i = 0; i < iA; ++i) slow_step(phase + (i << 4));

        // interior fast loop: no bounds handling, one base + constant offsets
        #pragma unroll 2
        for (int i = iA; i < iB; ++i) {
            const int k = phase + (i << 4);
            const float ts = tmin + ((float)k + 0.5f);
            const float px = sx + ts * dx;
            const float py = sy + ts * dy;
            const float pz = sz + ts * dz;
            const float fx = floorf(px), fy = floorf(py), fz = floorf(pz);
            const int ix = (int)fx, iy = (int)fy, iz = (int)fz;
            const float frx = px - fx, fry = py - fy, frz = pz - fz;
            const float wx1 = frx, wx0 = 1.0f - frx;
            const float wy1 = fry, wy0 = 1.0f - fry;
            const float wz1 = frz, wz0 = 1.0f - frz;

            const float* pa = volb + (((ix << 7) + iy) << 7) + iz;
            const float v000 = pa[0],                 v001 = pa[1];
            const float v010 = pa[VD],                v011 = pa[VD + 1];
            const float v100 = pa[VD * VD],           v101 = pa[VD * VD + 1];
            const float v110 = pa[VD * VD + VD],      v111 = pa[VD * VD + VD + 1];

            const float wxy00 = wx0 * wy0, wxy01 = wx0 * wy1;
            const float wxy10 = wx1 * wy0, wxy11 = wx1 * wy1;
            float smp = 0.0f;
            smp += v000 * (wxy00 * wz0);
            smp += v001 * (wxy00 * wz1);
            smp += v010 * (wxy01 * wz0);
            smp += v011 * (wxy01 * wz1);
            smp += v100 * (wxy10 * wz0);
            smp += v101 * (wxy10 * wz1);
            smp += v110 * (wxy11 * wz0);
            smp += v111 * (wxy11 * wz1);
            acc += smp;
        }

        #pragma unroll 1
        for (int i = iB; i < myn; ++i) slow_step(phase + (i << 4));

        // 16-lane butterfly reduce within the ray's lane group
        acc += __shfl_xor(acc, 1, 64);
        acc += __shfl_xor(acc, 2, 64);
        acc += __shfl_xor(acc, 4, 64);
        acc += __shfl_xor(acc, 8, 64);

        if (phase == 0) out[ray] = acc / 10.0f;
    }
}

extern "C" void kernel_launch(void* const* d_in, const int* in_sizes, int n_in,
                              void* d_out, int out_size, void* d_ws, size_t ws_size,
                              hipStream_t stream) {
    const float* vol = (const float*)d_in[0];   // (4,1,128,128,128) f32
    const float* tp  = (const float*)d_in[1];   // (4,6) f32
    float* out = (float*)d_out;                 // (4,1,128,128) f32
    float* ws  = (float*)d_ws;

    hipLaunchKernelGGL(drr_setup_kernel, dim3(1), dim3(64), 0, stream, tp, ws);

    const int total_threads = NB * VD * VD * LPR;   // 1048576
    hipLaunchKernelGGL(drr_proj_kernel, dim3(total_threads / 256), dim3(256), 0, stream,
                       vol, ws, out);
}